// Round 1
// baseline (1459.662 us; speedup 1.0000x reference)
//
#include <hip/hip_runtime.h>

typedef unsigned short ushort_t;
typedef unsigned int uint_t;

typedef __attribute__((ext_vector_type(8))) __bf16 bf16x8_t;
typedef __attribute__((ext_vector_type(8))) short s16x8;
typedef __attribute__((ext_vector_type(4))) float f32x4;

#define T_TOK 2048
#define H_DIM 2048
#define I_DIM 1024
#define N_EXP 64
#define TOPK 8
#define MT_MAX 6   // covers up to 768 tokens/expert (mean 256, std ~16)

__device__ inline f32x4 mfma_bf16(s16x8 a, s16x8 b, f32x4 c) {
  return __builtin_amdgcn_mfma_f32_16x16x32_bf16(
      __builtin_bit_cast(bf16x8_t, a), __builtin_bit_cast(bf16x8_t, b), c, 0, 0, 0);
}

__device__ inline ushort_t f2bf(float f) {
  uint_t u = __float_as_uint(f);
  u += 0x7FFFu + ((u >> 16) & 1u);   // round-to-nearest-even
  return (ushort_t)(u >> 16);
}
__device__ inline ushort4 f2bf4(float4 v) {
  ushort4 r;
  r.x = f2bf(v.x); r.y = f2bf(v.y); r.z = f2bf(v.z); r.w = f2bf(v.w);
  return r;
}

// ---------------- Router: logits[t][e] = sum_h x[t][h] * gw[e][h] (fp32 exact) ----------
__global__ __launch_bounds__(256) void router_kernel(const float* __restrict__ X,
                                                     const float* __restrict__ GW,
                                                     float* __restrict__ logits) {
  __shared__ float xs[4][H_DIM];
  int tid = threadIdx.x;
  int t0 = blockIdx.x * 4;
  const float4* src = (const float4*)(X + (size_t)t0 * H_DIM);
  float4* dst = (float4*)(&xs[0][0]);
#pragma unroll
  for (int j = 0; j < 8; ++j) dst[tid + 256 * j] = src[tid + 256 * j];
  __syncthreads();
  int wave = tid >> 6, lane = tid & 63;
  int t = t0 + wave;
  const float4* w = (const float4*)(GW + (size_t)lane * H_DIM);
  const float4* xr = (const float4*)(&xs[wave][0]);
  float acc = 0.f;
  for (int i = 0; i < H_DIM / 4; ++i) {
    float4 a = xr[i];
    float4 b = w[i];
    acc = fmaf(a.x, b.x, acc);
    acc = fmaf(a.y, b.y, acc);
    acc = fmaf(a.z, b.z, acc);
    acc = fmaf(a.w, b.w, acc);
  }
  logits[(size_t)t * N_EXP + lane] = acc;
}

// ---------------- Softmax + top-8 per token (one wave per token) -----------------------
__global__ __launch_bounds__(256) void topk_kernel(const float* __restrict__ logits,
                                                   int* __restrict__ counts,
                                                   int* __restrict__ sel_e,
                                                   float* __restrict__ sel_w) {
  int tid = threadIdx.x;
  int wave = tid >> 6, lane = tid & 63;
  int t = blockIdx.x * 4 + wave;
  float l = logits[(size_t)t * N_EXP + lane];
  float m = l;
#pragma unroll
  for (int s = 32; s; s >>= 1) m = fmaxf(m, __shfl_xor(m, s, 64));
  float p = __expf(l - m);
  float sum = p;
#pragma unroll
  for (int s = 32; s; s >>= 1) sum += __shfl_xor(sum, s, 64);
  float prob = p / sum;

  float val = l;
#pragma unroll
  for (int k = 0; k < TOPK; ++k) {
    float bv = val;
    int bi = lane;
#pragma unroll
    for (int s = 32; s; s >>= 1) {
      float ov = __shfl_xor(bv, s, 64);
      int oi = __shfl_xor(bi, s, 64);
      if (ov > bv || (ov == bv && oi < bi)) { bv = ov; bi = oi; }
    }
    float bw = __shfl(prob, bi, 64);
    if (lane == 0) {
      sel_e[t * TOPK + k] = bi;
      sel_w[t * TOPK + k] = bw;
      atomicAdd(&counts[bi], 1);
    }
    if (lane == bi) val = -INFINITY;
  }
}

// ---------------- Prefix sum over 64 expert counts -------------------------------------
__global__ void scan_kernel(const int* __restrict__ counts, int* __restrict__ offsets,
                            int* __restrict__ cursor) {
  if (threadIdx.x == 0) {
    int acc = 0;
    for (int e = 0; e < N_EXP; ++e) { offsets[e] = acc; acc += counts[e]; }
    offsets[N_EXP] = acc;
  }
  if (threadIdx.x < N_EXP) cursor[threadIdx.x] = 0;
}

// ---------------- Assign packed rows ---------------------------------------------------
__global__ __launch_bounds__(256) void assign_kernel(const int* __restrict__ sel_e,
                                                     const float* __restrict__ sel_w,
                                                     const int* __restrict__ offsets,
                                                     int* __restrict__ cursor,
                                                     int* __restrict__ token_of,
                                                     float* __restrict__ weight_of) {
  int idx = blockIdx.x * 256 + threadIdx.x;  // 0..16383
  int t = idx >> 3;
  int e = sel_e[idx];
  float w = sel_w[idx];
  int r = offsets[e] + atomicAdd(&cursor[e], 1);
  token_of[r] = t;
  weight_of[r] = w;
}

// ---------------- Fused gate+up GEMM + SiLU -> act (bf16) ------------------------------
// grid: 64 experts x MT_MAX m-tiles x 8 n-tiles; tile 128x128, K-step 32
__global__ __launch_bounds__(256) void gateup_kernel(const float* __restrict__ X,
                                                     const float* __restrict__ Wg,
                                                     const float* __restrict__ Wu,
                                                     const int* __restrict__ offsets,
                                                     const int* __restrict__ token_of,
                                                     ushort_t* __restrict__ act) {
  int bid = blockIdx.x;
  int e = bid / (MT_MAX * 8);
  int mt = (bid % (MT_MAX * 8)) / 8;
  int nt = bid % 8;
  int base = offsets[e];
  int Me = offsets[e + 1] - base;
  if (mt * 128 >= Me) return;

  __shared__ ushort_t As[128 * 40];
  __shared__ ushort_t Bgs[128 * 40];
  __shared__ ushort_t Bus[128 * 40];
  __shared__ int stok[128];

  int tid = threadIdx.x;
  if (tid < 128) {
    int gm = mt * 128 + tid;
    int cm = gm < Me ? gm : (Me - 1);
    stok[tid] = token_of[base + cm];
  }
  __syncthreads();

  int row = tid >> 1;
  int kh = (tid & 1) * 16;
  int wave = tid >> 6, lane = tid & 63;
  int wm = wave >> 1, wn = wave & 1;

  int trow = stok[row];
  const float* Arow = X + (size_t)trow * H_DIM;
  const float* Bgr = Wg + ((size_t)e * I_DIM + nt * 128 + row) * H_DIM;
  const float* Bur = Wu + ((size_t)e * I_DIM + nt * 128 + row) * H_DIM;

  f32x4 accg[4][4], accu[4][4];
#pragma unroll
  for (int i = 0; i < 4; ++i)
#pragma unroll
    for (int j = 0; j < 4; ++j) { accg[i][j] = (f32x4)0.f; accu[i][j] = (f32x4)0.f; }

  for (int k0 = 0; k0 < H_DIM; k0 += 32) {
    float4 a0 = *(const float4*)(Arow + k0 + kh + 0);
    float4 a1 = *(const float4*)(Arow + k0 + kh + 4);
    float4 a2 = *(const float4*)(Arow + k0 + kh + 8);
    float4 a3 = *(const float4*)(Arow + k0 + kh + 12);
    float4 g0 = *(const float4*)(Bgr + k0 + kh + 0);
    float4 g1 = *(const float4*)(Bgr + k0 + kh + 4);
    float4 g2 = *(const float4*)(Bgr + k0 + kh + 8);
    float4 g3 = *(const float4*)(Bgr + k0 + kh + 12);
    float4 u0 = *(const float4*)(Bur + k0 + kh + 0);
    float4 u1 = *(const float4*)(Bur + k0 + kh + 4);
    float4 u2 = *(const float4*)(Bur + k0 + kh + 8);
    float4 u3 = *(const float4*)(Bur + k0 + kh + 12);
    __syncthreads();  // previous compute done before overwrite
    *(ushort4*)&As[row * 40 + kh + 0] = f2bf4(a0);
    *(ushort4*)&As[row * 40 + kh + 4] = f2bf4(a1);
    *(ushort4*)&As[row * 40 + kh + 8] = f2bf4(a2);
    *(ushort4*)&As[row * 40 + kh + 12] = f2bf4(a3);
    *(ushort4*)&Bgs[row * 40 + kh + 0] = f2bf4(g0);
    *(ushort4*)&Bgs[row * 40 + kh + 4] = f2bf4(g1);
    *(ushort4*)&Bgs[row * 40 + kh + 8] = f2bf4(g2);
    *(ushort4*)&Bgs[row * 40 + kh + 12] = f2bf4(g3);
    *(ushort4*)&Bus[row * 40 + kh + 0] = f2bf4(u0);
    *(ushort4*)&Bus[row * 40 + kh + 4] = f2bf4(u1);
    *(ushort4*)&Bus[row * 40 + kh + 8] = f2bf4(u2);
    *(ushort4*)&Bus[row * 40 + kh + 12] = f2bf4(u3);
    __syncthreads();

    s16x8 af[4], bg[4], bu[4];
#pragma unroll
    for (int mf = 0; mf < 4; ++mf)
      af[mf] = *(const s16x8*)&As[(wm * 64 + mf * 16 + (lane & 15)) * 40 + (lane >> 4) * 8];
#pragma unroll
    for (int nf = 0; nf < 4; ++nf) {
      bg[nf] = *(const s16x8*)&Bgs[(wn * 64 + nf * 16 + (lane & 15)) * 40 + (lane >> 4) * 8];
      bu[nf] = *(const s16x8*)&Bus[(wn * 64 + nf * 16 + (lane & 15)) * 40 + (lane >> 4) * 8];
    }
#pragma unroll
    for (int mf = 0; mf < 4; ++mf)
#pragma unroll
      for (int nf = 0; nf < 4; ++nf) {
        accg[mf][nf] = mfma_bf16(af[mf], bg[nf], accg[mf][nf]);
        accu[mf][nf] = mfma_bf16(af[mf], bu[nf], accu[mf][nf]);
      }
  }

  // epilogue: act = silu(g)*u -> bf16
#pragma unroll
  for (int mf = 0; mf < 4; ++mf)
#pragma unroll
    for (int nf = 0; nf < 4; ++nf) {
      f32x4 g = accg[mf][nf], u = accu[mf][nf];
#pragma unroll
      for (int r = 0; r < 4; ++r) {
        int mloc = wm * 64 + mf * 16 + (lane >> 4) * 4 + r;
        int gm = mt * 128 + mloc;
        if (gm < Me) {
          float gv = g[r], uv = u[r];
          float s = gv / (1.f + __expf(-gv));
          int col = nt * 128 + wn * 64 + nf * 16 + (lane & 15);
          act[(size_t)(base + gm) * I_DIM + col] = f2bf(s * uv);
        }
      }
    }
}

// ---------------- Down GEMM + weighted scatter to out ----------------------------------
// grid: 64 experts x MT_MAX m-tiles x 16 n-tiles; tile 128x128, K-step 32
__global__ __launch_bounds__(256) void down_kernel(const ushort_t* __restrict__ act,
                                                   const float* __restrict__ Wd,
                                                   const int* __restrict__ offsets,
                                                   const int* __restrict__ token_of,
                                                   const float* __restrict__ weight_of,
                                                   float* __restrict__ out) {
  int bid = blockIdx.x;
  int e = bid / (MT_MAX * 16);
  int mt = (bid % (MT_MAX * 16)) / 16;
  int nt = bid % 16;
  int base = offsets[e];
  int Me = offsets[e + 1] - base;
  if (mt * 128 >= Me) return;

  __shared__ ushort_t As[128 * 40];
  __shared__ ushort_t Bs[128 * 40];
  __shared__ int stok[128];
  __shared__ float sw[128];

  int tid = threadIdx.x;
  if (tid < 128) {
    int gm = mt * 128 + tid;
    int ok = gm < Me;
    int cm = ok ? gm : (Me - 1);
    stok[tid] = token_of[base + cm];
    sw[tid] = ok ? weight_of[base + gm] : 0.f;
  }
  __syncthreads();

  int row = tid >> 1;
  int kh = (tid & 1) * 16;
  int wave = tid >> 6, lane = tid & 63;
  int wm = wave >> 1, wn = wave & 1;

  int rclamp = mt * 128 + row;
  if (rclamp >= Me) rclamp = Me - 1;
  const ushort_t* Arow = act + (size_t)(base + rclamp) * I_DIM;
  const float* Brow = Wd + ((size_t)e * H_DIM + nt * 128 + row) * I_DIM;

  f32x4 acc[4][4];
#pragma unroll
  for (int i = 0; i < 4; ++i)
#pragma unroll
    for (int j = 0; j < 4; ++j) acc[i][j] = (f32x4)0.f;

  for (int k0 = 0; k0 < I_DIM; k0 += 32) {
    s16x8 av0 = *(const s16x8*)(Arow + k0 + kh + 0);
    s16x8 av1 = *(const s16x8*)(Arow + k0 + kh + 8);
    float4 b0 = *(const float4*)(Brow + k0 + kh + 0);
    float4 b1 = *(const float4*)(Brow + k0 + kh + 4);
    float4 b2 = *(const float4*)(Brow + k0 + kh + 8);
    float4 b3 = *(const float4*)(Brow + k0 + kh + 12);
    __syncthreads();
    *(s16x8*)&As[row * 40 + kh + 0] = av0;
    *(s16x8*)&As[row * 40 + kh + 8] = av1;
    *(ushort4*)&Bs[row * 40 + kh + 0] = f2bf4(b0);
    *(ushort4*)&Bs[row * 40 + kh + 4] = f2bf4(b1);
    *(ushort4*)&Bs[row * 40 + kh + 8] = f2bf4(b2);
    *(ushort4*)&Bs[row * 40 + kh + 12] = f2bf4(b3);
    __syncthreads();

    s16x8 af[4], bf[4];
#pragma unroll
    for (int mf = 0; mf < 4; ++mf)
      af[mf] = *(const s16x8*)&As[(wm * 64 + mf * 16 + (lane & 15)) * 40 + (lane >> 4) * 8];
#pragma unroll
    for (int nf = 0; nf < 4; ++nf)
      bf[nf] = *(const s16x8*)&Bs[(wn * 64 + nf * 16 + (lane & 15)) * 40 + (lane >> 4) * 8];
#pragma unroll
    for (int mf = 0; mf < 4; ++mf)
#pragma unroll
      for (int nf = 0; nf < 4; ++nf)
        acc[mf][nf] = mfma_bf16(af[mf], bf[nf], acc[mf][nf]);
  }

#pragma unroll
  for (int mf = 0; mf < 4; ++mf)
#pragma unroll
    for (int nf = 0; nf < 4; ++nf) {
      f32x4 v = acc[mf][nf];
#pragma unroll
      for (int r = 0; r < 4; ++r) {
        int mloc = wm * 64 + mf * 16 + (lane >> 4) * 4 + r;
        int gm = mt * 128 + mloc;
        if (gm < Me) {
          int t = stok[mloc];
          float w = sw[mloc];
          int h = nt * 128 + wn * 64 + nf * 16 + (lane & 15);
          unsafeAtomicAdd(&out[(size_t)t * H_DIM + h], w * v[r]);
        }
      }
    }
}

// ---------------------------------------------------------------------------------------
extern "C" void kernel_launch(void* const* d_in, const int* in_sizes, int n_in,
                              void* d_out, int out_size, void* d_ws, size_t ws_size,
                              hipStream_t stream) {
  const float* X = (const float*)d_in[0];
  const float* GW = (const float*)d_in[1];
  const float* Wg = (const float*)d_in[2];
  const float* Wu = (const float*)d_in[3];
  const float* Wd = (const float*)d_in[4];
  float* out = (float*)d_out;
  float* logits = out + (size_t)T_TOK * H_DIM;

  char* ws = (char*)d_ws;
  int* counts = (int*)ws;                       // 256 B
  int* cursor = (int*)(ws + 256);               // 256 B
  int* offsets = (int*)(ws + 512);              // 260 B
  int* sel_e = (int*)(ws + 1024);               // 64 KB
  float* sel_w = (float*)(ws + 1024 + 65536);   // 64 KB
  int* token_of = (int*)(ws + 1024 + 2 * 65536);
  float* weight_of = (float*)(ws + 1024 + 3 * 65536);
  ushort_t* act = (ushort_t*)(ws + 524288);     // 16384*1024*2 = 32 MB

  hipMemsetAsync(out, 0, (size_t)T_TOK * H_DIM * sizeof(float), stream);
  hipMemsetAsync(ws, 0, 1024, stream);

  router_kernel<<<T_TOK / 4, 256, 0, stream>>>(X, GW, logits);
  topk_kernel<<<T_TOK / 4, 256, 0, stream>>>(logits, counts, sel_e, sel_w);
  scan_kernel<<<1, 64, 0, stream>>>(counts, offsets, cursor);
  assign_kernel<<<(T_TOK * TOPK) / 256, 256, 0, stream>>>(sel_e, sel_w, offsets, cursor,
                                                          token_of, weight_of);
  gateup_kernel<<<N_EXP * MT_MAX * 8, 256, 0, stream>>>(X, Wg, Wu, offsets, token_of, act);
  down_kernel<<<N_EXP * MT_MAX * 16, 256, 0, stream>>>(act, Wd, offsets, token_of,
                                                       weight_of, out);
}

// Round 2
// 1285.094 us; speedup vs baseline: 1.1358x; 1.1358x over previous
//
#include <hip/hip_runtime.h>

typedef unsigned short ushort_t;
typedef unsigned int uint_t;

typedef __attribute__((ext_vector_type(8))) __bf16 bf16x8_t;
typedef __attribute__((ext_vector_type(8))) short s16x8;
typedef __attribute__((ext_vector_type(4))) float f32x4;

#define T_TOK 2048
#define H_DIM 2048
#define I_DIM 1024
#define N_EXP 64
#define TOPK 8
#define MT_MAX 6   // covers up to 768 tokens/expert (mean 256)

// Raw barrier: does NOT drain vmcnt -> in-flight global loads (which only
// write private VGPRs) legally stay outstanding across it.
#define BAR_RAW()  asm volatile("s_barrier" ::: "memory")
// LDS-visibility barrier: drain own ds_writes (lgkm) then barrier; vmcnt
// untouched so prefetch loads stay in flight.
#define BAR_LGKM() asm volatile("s_waitcnt lgkmcnt(0)\n\ts_barrier" ::: "memory")

__device__ inline f32x4 mfma_bf16(s16x8 a, s16x8 b, f32x4 c) {
  return __builtin_amdgcn_mfma_f32_16x16x32_bf16(
      __builtin_bit_cast(bf16x8_t, a), __builtin_bit_cast(bf16x8_t, b), c, 0, 0, 0);
}

__device__ inline ushort_t f2bf(float f) {
  uint_t u = __float_as_uint(f);
  u += 0x7FFFu + ((u >> 16) & 1u);   // round-to-nearest-even
  return (ushort_t)(u >> 16);
}
__device__ inline ushort4 f2bf4(float4 v) {
  ushort4 r;
  r.x = f2bf(v.x); r.y = f2bf(v.y); r.z = f2bf(v.z); r.w = f2bf(v.w);
  return r;
}

// ---------------- Router: logits[t][e] = sum_h x[t][h] * gw[e][h] (fp32 exact) ----------
__global__ __launch_bounds__(256) void router_kernel(const float* __restrict__ X,
                                                     const float* __restrict__ GW,
                                                     float* __restrict__ logits) {
  __shared__ float xs[4][H_DIM];
  int tid = threadIdx.x;
  int t0 = blockIdx.x * 4;
  const float4* src = (const float4*)(X + (size_t)t0 * H_DIM);
  float4* dst = (float4*)(&xs[0][0]);
#pragma unroll
  for (int j = 0; j < 8; ++j) dst[tid + 256 * j] = src[tid + 256 * j];
  __syncthreads();
  int wave = tid >> 6, lane = tid & 63;
  int t = t0 + wave;
  const float4* w = (const float4*)(GW + (size_t)lane * H_DIM);
  const float4* xr = (const float4*)(&xs[wave][0]);
  float acc = 0.f;
  for (int i = 0; i < H_DIM / 4; ++i) {
    float4 a = xr[i];
    float4 b = w[i];
    acc = fmaf(a.x, b.x, acc);
    acc = fmaf(a.y, b.y, acc);
    acc = fmaf(a.z, b.z, acc);
    acc = fmaf(a.w, b.w, acc);
  }
  logits[(size_t)t * N_EXP + lane] = acc;
}

// ---------------- Softmax + top-8 per token (one wave per token) -----------------------
__global__ __launch_bounds__(256) void topk_kernel(const float* __restrict__ logits,
                                                   int* __restrict__ counts,
                                                   int* __restrict__ sel_e,
                                                   float* __restrict__ sel_w) {
  int tid = threadIdx.x;
  int wave = tid >> 6, lane = tid & 63;
  int t = blockIdx.x * 4 + wave;
  float l = logits[(size_t)t * N_EXP + lane];
  float m = l;
#pragma unroll
  for (int s = 32; s; s >>= 1) m = fmaxf(m, __shfl_xor(m, s, 64));
  float p = __expf(l - m);
  float sum = p;
#pragma unroll
  for (int s = 32; s; s >>= 1) sum += __shfl_xor(sum, s, 64);
  float prob = p / sum;

  float val = l;
#pragma unroll
  for (int k = 0; k < TOPK; ++k) {
    float bv = val;
    int bi = lane;
#pragma unroll
    for (int s = 32; s; s >>= 1) {
      float ov = __shfl_xor(bv, s, 64);
      int oi = __shfl_xor(bi, s, 64);
      if (ov > bv || (ov == bv && oi < bi)) { bv = ov; bi = oi; }
    }
    float bw = __shfl(prob, bi, 64);
    if (lane == 0) {
      sel_e[t * TOPK + k] = bi;
      sel_w[t * TOPK + k] = bw;
      atomicAdd(&counts[bi], 1);
    }
    if (lane == bi) val = -INFINITY;
  }
}

// ---------------- Prefix sum over 64 expert counts -------------------------------------
__global__ void scan_kernel(const int* __restrict__ counts, int* __restrict__ offsets,
                            int* __restrict__ cursor) {
  if (threadIdx.x == 0) {
    int acc = 0;
    for (int e = 0; e < N_EXP; ++e) { offsets[e] = acc; acc += counts[e]; }
    offsets[N_EXP] = acc;
  }
  if (threadIdx.x < N_EXP) cursor[threadIdx.x] = 0;
}

// ---------------- Assign packed rows ---------------------------------------------------
__global__ __launch_bounds__(256) void assign_kernel(const int* __restrict__ sel_e,
                                                     const float* __restrict__ sel_w,
                                                     const int* __restrict__ offsets,
                                                     int* __restrict__ cursor,
                                                     int* __restrict__ token_of,
                                                     float* __restrict__ weight_of) {
  int idx = blockIdx.x * 256 + threadIdx.x;  // 0..16383
  int t = idx >> 3;
  int e = sel_e[idx];
  float w = sel_w[idx];
  int r = offsets[e] + atomicAdd(&cursor[e], 1);
  token_of[r] = t;
  weight_of[r] = w;
}

// ---------------- Fused gate+up GEMM + SiLU -> act (bf16), pipelined -------------------
// grid: 64 experts x MT_MAX m-tiles x 8 n-tiles; tile 128x128, K-step 32
__global__ __launch_bounds__(256) void gateup_kernel(const float* __restrict__ X,
                                                     const float* __restrict__ Wg,
                                                     const float* __restrict__ Wu,
                                                     const int* __restrict__ offsets,
                                                     const int* __restrict__ token_of,
                                                     ushort_t* __restrict__ act) {
  int bid = blockIdx.x;
  int e = bid / (MT_MAX * 8);
  int mt = (bid % (MT_MAX * 8)) / 8;
  int nt = bid % 8;
  int base = offsets[e];
  int Me = offsets[e + 1] - base;
  if (mt * 128 >= Me) return;

  __shared__ ushort_t As[128 * 40];
  __shared__ ushort_t Bgs[128 * 40];
  __shared__ ushort_t Bus[128 * 40];
  __shared__ int stok[128];

  int tid = threadIdx.x;
  if (tid < 128) {
    int gm = mt * 128 + tid;
    int cm = gm < Me ? gm : (Me - 1);
    stok[tid] = token_of[base + cm];
  }
  __syncthreads();

  int row = tid >> 1;
  int kh = (tid & 1) * 16;
  int wave = tid >> 6, lane = tid & 63;
  int wm = wave >> 1, wn = wave & 1;

  int trow = stok[row];
  const float* Arow = X + (size_t)trow * H_DIM + kh;
  const float* Bgr = Wg + ((size_t)e * I_DIM + nt * 128 + row) * H_DIM + kh;
  const float* Bur = Wu + ((size_t)e * I_DIM + nt * 128 + row) * H_DIM + kh;

  f32x4 accg[4][4], accu[4][4];
#pragma unroll
  for (int i = 0; i < 4; ++i)
#pragma unroll
    for (int j = 0; j < 4; ++j) { accg[i][j] = (f32x4)0.f; accu[i][j] = (f32x4)0.f; }

  float4 ra[4], rg[4], ru[4];
#pragma unroll
  for (int j = 0; j < 4; ++j) {
    ra[j] = *(const float4*)(Arow + 4 * j);
    rg[j] = *(const float4*)(Bgr + 4 * j);
    ru[j] = *(const float4*)(Bur + 4 * j);
  }

  for (int k0 = 0; k0 < H_DIM; k0 += 32) {
    BAR_RAW();  // prev iter's ds_reads all consumed; prefetch loads cross freely
#pragma unroll
    for (int j = 0; j < 4; ++j) {
      *(ushort4*)&As[row * 40 + kh + 4 * j] = f2bf4(ra[j]);
      *(ushort4*)&Bgs[row * 40 + kh + 4 * j] = f2bf4(rg[j]);
      *(ushort4*)&Bus[row * 40 + kh + 4 * j] = f2bf4(ru[j]);
    }
    if (k0 + 32 < H_DIM) {
      int kn = k0 + 32;
#pragma unroll
      for (int j = 0; j < 4; ++j) {
        ra[j] = *(const float4*)(Arow + kn + 4 * j);
        rg[j] = *(const float4*)(Bgr + kn + 4 * j);
        ru[j] = *(const float4*)(Bur + kn + 4 * j);
      }
    }
    BAR_LGKM();  // ds_writes visible; vmcnt untouched (prefetch in flight)

    s16x8 af[4], bg[4], bu[4];
#pragma unroll
    for (int mf = 0; mf < 4; ++mf)
      af[mf] = *(const s16x8*)&As[(wm * 64 + mf * 16 + (lane & 15)) * 40 + (lane >> 4) * 8];
#pragma unroll
    for (int nf = 0; nf < 4; ++nf) {
      bg[nf] = *(const s16x8*)&Bgs[(wn * 64 + nf * 16 + (lane & 15)) * 40 + (lane >> 4) * 8];
      bu[nf] = *(const s16x8*)&Bus[(wn * 64 + nf * 16 + (lane & 15)) * 40 + (lane >> 4) * 8];
    }
#pragma unroll
    for (int mf = 0; mf < 4; ++mf)
#pragma unroll
      for (int nf = 0; nf < 4; ++nf) {
        accg[mf][nf] = mfma_bf16(af[mf], bg[nf], accg[mf][nf]);
        accu[mf][nf] = mfma_bf16(af[mf], bu[nf], accu[mf][nf]);
      }
  }

  // epilogue: act = silu(g)*u -> bf16
#pragma unroll
  for (int mf = 0; mf < 4; ++mf)
#pragma unroll
    for (int nf = 0; nf < 4; ++nf) {
      f32x4 g = accg[mf][nf], u = accu[mf][nf];
#pragma unroll
      for (int r = 0; r < 4; ++r) {
        int mloc = wm * 64 + mf * 16 + (lane >> 4) * 4 + r;
        int gm = mt * 128 + mloc;
        if (gm < Me) {
          float gv = g[r], uv = u[r];
          float s = gv / (1.f + __expf(-gv));
          int col = nt * 128 + wn * 64 + nf * 16 + (lane & 15);
          act[(size_t)(base + gm) * I_DIM + col] = f2bf(s * uv);
        }
      }
    }
}

// ---------------- Down GEMM + weighted scatter to out, pipelined -----------------------
// grid: 64 experts x MT_MAX m-tiles x 16 n-tiles; tile 128x128, K-step 32
__global__ __launch_bounds__(256) void down_kernel(const ushort_t* __restrict__ act,
                                                   const float* __restrict__ Wd,
                                                   const int* __restrict__ offsets,
                                                   const int* __restrict__ token_of,
                                                   const float* __restrict__ weight_of,
                                                   float* __restrict__ out) {
  int bid = blockIdx.x;
  int e = bid / (MT_MAX * 16);
  int mt = (bid % (MT_MAX * 16)) / 16;
  int nt = bid % 16;
  int base = offsets[e];
  int Me = offsets[e + 1] - base;
  if (mt * 128 >= Me) return;

  __shared__ ushort_t As[128 * 40];
  __shared__ ushort_t Bs[128 * 40];
  __shared__ int stok[128];
  __shared__ float sw[128];

  int tid = threadIdx.x;
  if (tid < 128) {
    int gm = mt * 128 + tid;
    int ok = gm < Me;
    int cm = ok ? gm : (Me - 1);
    stok[tid] = token_of[base + cm];
    sw[tid] = ok ? weight_of[base + gm] : 0.f;
  }
  __syncthreads();

  int row = tid >> 1;
  int kh = (tid & 1) * 16;
  int wave = tid >> 6, lane = tid & 63;
  int wm = wave >> 1, wn = wave & 1;

  int rclamp = mt * 128 + row;
  if (rclamp >= Me) rclamp = Me - 1;
  const ushort_t* Arow = act + (size_t)(base + rclamp) * I_DIM + kh;
  const float* Brow = Wd + ((size_t)e * H_DIM + nt * 128 + row) * I_DIM + kh;

  f32x4 acc[4][4];
#pragma unroll
  for (int i = 0; i < 4; ++i)
#pragma unroll
    for (int j = 0; j < 4; ++j) acc[i][j] = (f32x4)0.f;

  s16x8 rav[2];
  float4 rb[4];
  rav[0] = *(const s16x8*)(Arow + 0);
  rav[1] = *(const s16x8*)(Arow + 8);
#pragma unroll
  for (int j = 0; j < 4; ++j) rb[j] = *(const float4*)(Brow + 4 * j);

  for (int k0 = 0; k0 < I_DIM; k0 += 32) {
    BAR_RAW();
    *(s16x8*)&As[row * 40 + kh + 0] = rav[0];
    *(s16x8*)&As[row * 40 + kh + 8] = rav[1];
#pragma unroll
    for (int j = 0; j < 4; ++j) *(ushort4*)&Bs[row * 40 + kh + 4 * j] = f2bf4(rb[j]);
    if (k0 + 32 < I_DIM) {
      int kn = k0 + 32;
      rav[0] = *(const s16x8*)(Arow + kn + 0);
      rav[1] = *(const s16x8*)(Arow + kn + 8);
#pragma unroll
      for (int j = 0; j < 4; ++j) rb[j] = *(const float4*)(Brow + kn + 4 * j);
    }
    BAR_LGKM();

    s16x8 af[4], bf[4];
#pragma unroll
    for (int mf = 0; mf < 4; ++mf)
      af[mf] = *(const s16x8*)&As[(wm * 64 + mf * 16 + (lane & 15)) * 40 + (lane >> 4) * 8];
#pragma unroll
    for (int nf = 0; nf < 4; ++nf)
      bf[nf] = *(const s16x8*)&Bs[(wn * 64 + nf * 16 + (lane & 15)) * 40 + (lane >> 4) * 8];
#pragma unroll
    for (int mf = 0; mf < 4; ++mf)
#pragma unroll
      for (int nf = 0; nf < 4; ++nf)
        acc[mf][nf] = mfma_bf16(af[mf], bf[nf], acc[mf][nf]);
  }

#pragma unroll
  for (int mf = 0; mf < 4; ++mf)
#pragma unroll
    for (int nf = 0; nf < 4; ++nf) {
      f32x4 v = acc[mf][nf];
#pragma unroll
      for (int r = 0; r < 4; ++r) {
        int mloc = wm * 64 + mf * 16 + (lane >> 4) * 4 + r;
        int gm = mt * 128 + mloc;
        if (gm < Me) {
          int t = stok[mloc];
          float w = sw[mloc];
          int h = nt * 128 + wn * 64 + nf * 16 + (lane & 15);
          unsafeAtomicAdd(&out[(size_t)t * H_DIM + h], w * v[r]);
        }
      }
    }
}

// ---------------------------------------------------------------------------------------
extern "C" void kernel_launch(void* const* d_in, const int* in_sizes, int n_in,
                              void* d_out, int out_size, void* d_ws, size_t ws_size,
                              hipStream_t stream) {
  const float* X = (const float*)d_in[0];
  const float* GW = (const float*)d_in[1];
  const float* Wg = (const float*)d_in[2];
  const float* Wu = (const float*)d_in[3];
  const float* Wd = (const float*)d_in[4];
  float* out = (float*)d_out;
  float* logits = out + (size_t)T_TOK * H_DIM;

  char* ws = (char*)d_ws;
  int* counts = (int*)ws;                       // 256 B
  int* cursor = (int*)(ws + 256);               // 256 B
  int* offsets = (int*)(ws + 512);              // 260 B
  int* sel_e = (int*)(ws + 1024);               // 64 KB
  float* sel_w = (float*)(ws + 1024 + 65536);   // 64 KB
  int* token_of = (int*)(ws + 1024 + 2 * 65536);
  float* weight_of = (float*)(ws + 1024 + 3 * 65536);
  ushort_t* act = (ushort_t*)(ws + 524288);     // 16384*1024*2 = 32 MB

  hipMemsetAsync(out, 0, (size_t)T_TOK * H_DIM * sizeof(float), stream);
  hipMemsetAsync(ws, 0, 1024, stream);

  router_kernel<<<T_TOK / 4, 256, 0, stream>>>(X, GW, logits);
  topk_kernel<<<T_TOK / 4, 256, 0, stream>>>(logits, counts, sel_e, sel_w);
  scan_kernel<<<1, 64, 0, stream>>>(counts, offsets, cursor);
  assign_kernel<<<(T_TOK * TOPK) / 256, 256, 0, stream>>>(sel_e, sel_w, offsets, cursor,
                                                          token_of, weight_of);
  gateup_kernel<<<N_EXP * MT_MAX * 8, 256, 0, stream>>>(X, Wg, Wu, offsets, token_of, act);
  down_kernel<<<N_EXP * MT_MAX * 16, 256, 0, stream>>>(act, Wd, offsets, token_of,
                                                       weight_of, out);
}